// Round 4
// baseline (224.245 us; speedup 1.0000x reference)
//
#include <hip/hip_runtime.h>
#include <hip/hip_cooperative_groups.h>

namespace cg = cooperative_groups;

// BahdanauAttnDecoderRNN single-step decode, MI355X.
// Reference dead code: softmax over size-1 axis => attn_weights == 1.0;
// attn_W/attn_b/scores dead; attn_applied = colsum(encoder_outputs).
// Live work ~178 MB f32 reads (Wout 131 MB dominant) => ~28 us HBM roofline.
// Round-3 failure: fixed grid=1024 cooperative launch was rejected by the
// runtime (unchecked error -> zeros). This version: grid-ADAPTIVE phases
// (task-stride loops), occupancy-derived grid, and a 4-dispatch fallback.

namespace {
constexpr int H = 1024;
constexpr int V = 32000;
constexpr int S = 2048;
constexpr int NTHR = 256;
constexpr int CS_TASKS = 32;                       // colsum chunks (64 rows each)
constexpr int CS_ROWS = S / CS_TASKS;              // 64
constexpr int MV_TASKS = 768;                      // 3072 GRU rows / 4 per block
constexpr int P0_TASKS = CS_TASKS + MV_TASKS + 1;  // 801 (+1: attn ones)
constexpr int P2_TASKS = 2000;                     // 32000 logit rows / 16 per block
constexpr int P3_TASKS = 125;                      // 32000 / 256
constexpr int MAXNB = 1024;
constexpr int MAXW = 8192;                         // partm/parts capacity (waves)
}

struct Ptrs {
    const int* word; const float* hin; const float* enc; const float* emb;
    const float* Wih; const float* Whh; const float* bih; const float* bhh;
    const float* Wout; const float* bout;
    float* out; float* part; float* gi; float* gh; float* partm; float* parts;
};

__device__ __forceinline__ float wave_sum(float v) {
#pragma unroll
    for (int off = 32; off > 0; off >>= 1) v += __shfl_xor(v, off, 64);
    return v;
}
__device__ __forceinline__ float wave_max(float v) {
#pragma unroll
    for (int off = 32; off > 0; off >>= 1) v = fmaxf(v, __shfl_xor(v, off, 64));
    return v;
}

// P0: colsum partials (disjoint chunks) + gh & emb-half of gi + attn ones.
__device__ void phase0(const Ptrs& P, int nb, int bid, int t, int lane, int w) {
    for (int task = bid; task < P0_TASKS; task += nb) {
        if (task < CS_TASKS) {
            const float4* e = (const float4*)P.enc + (size_t)task * CS_ROWS * (H / 4) + t;
            float4 acc = make_float4(0.f, 0.f, 0.f, 0.f);
#pragma unroll 8
            for (int r = 0; r < CS_ROWS; ++r) {
                float4 v = e[(size_t)r * (H / 4)];
                acc.x += v.x; acc.y += v.y; acc.z += v.z; acc.w += v.w;
            }
            ((float4*)P.part)[task * (H / 4) + t] = acc;
        } else if (task < CS_TASKS + MV_TASKS) {
            const int row = (task - CS_TASKS) * 4 + w;  // < 3072
            const float4* wh = (const float4*)P.Whh + (size_t)row * (H / 4);
            const float4* xh = (const float4*)P.hin;
            const float4* wi = (const float4*)P.Wih + (size_t)row * (2 * H / 4);
            const float4* er = (const float4*)P.emb + (size_t)P.word[0] * (H / 4);
            float ah = 0.f, ai = 0.f;
#pragma unroll
            for (int it = 0; it < 4; ++it) {
                const int idx = it * 64 + lane;
                float4 a4 = wh[idx], x4 = xh[idx];
                ah += a4.x * x4.x + a4.y * x4.y + a4.z * x4.z + a4.w * x4.w;
                float4 b4 = wi[idx], e4 = er[idx];
                e4.x = fmaxf(e4.x, 0.f); e4.y = fmaxf(e4.y, 0.f);
                e4.z = fmaxf(e4.z, 0.f); e4.w = fmaxf(e4.w, 0.f);
                ai += b4.x * e4.x + b4.y * e4.y + b4.z * e4.z + b4.w * e4.w;
            }
            ah = wave_sum(ah);
            ai = wave_sum(ai);
            if (lane == 0) {
                P.gh[row] = ah + P.bhh[row];
                P.gi[row] = ai + P.bih[row];  // + colsum-half in P1
            }
        } else {
            // attn_weights exactly 1.0 (softmax over size-1 axis)
#pragma unroll
            for (int k = 0; k < S / NTHR; ++k) P.out[V + H + k * NTHR + t] = 1.0f;
        }
    }
}

// P1: reduce colsum partials (per block, L2) -> relu in LDS -> colsum-half of gi.
__device__ void phase1(const Ptrs& P, int nb, int bid, int t, int lane, int w, float4* rn) {
    float4 acc = make_float4(0.f, 0.f, 0.f, 0.f);
#pragma unroll
    for (int p = 0; p < CS_TASKS; ++p) {
        float4 v = ((const float4*)P.part)[p * (H / 4) + t];
        acc.x += v.x; acc.y += v.y; acc.z += v.z; acc.w += v.w;
    }
    acc.x = fmaxf(acc.x, 0.f); acc.y = fmaxf(acc.y, 0.f);
    acc.z = fmaxf(acc.z, 0.f); acc.w = fmaxf(acc.w, 0.f);
    rn[t] = acc;
    __syncthreads();
    for (int task = bid; task < MV_TASKS; task += nb) {
        const int row = task * 4 + w;  // < 3072
        const float4* wr = (const float4*)P.Wih + (size_t)row * (2 * H / 4) + (H / 4);
        float a = 0.f;
#pragma unroll
        for (int it = 0; it < 4; ++it) {
            const int idx = it * 64 + lane;
            float4 wv = wr[idx], x = rn[idx];
            a += wv.x * x.x + wv.y * x.y + wv.z * x.z + wv.w * x.w;
        }
        a = wave_sum(a);
        if (lane == 0) P.gi[row] += a;
    }
}

// P2: h_new redundant per block (LDS) + logits matvec + per-wave sm partials.
__device__ void phase2(const Ptrs& P, int nb, int bid, int t, int lane, int w, float* hnew) {
#pragma unroll
    for (int q = 0; q < 4; ++q) {
        const int j = q * NTHR + t;
        const float r = 1.f / (1.f + expf(-(P.gi[j] + P.gh[j])));
        const float z = 1.f / (1.f + expf(-(P.gi[H + j] + P.gh[H + j])));
        const float n = tanhf(P.gi[2 * H + j] + r * P.gh[2 * H + j]);
        const float hv = (1.f - z) * n + z * P.hin[j];
        hnew[j] = hv;
        if (bid == 0) P.out[V + j] = hv;  // hidden-state output
    }
    __syncthreads();
    const float4* hn4 = (const float4*)hnew;
    float m = -3.4e38f, ssum = 0.f;
    for (int task = bid; task < P2_TASKS; task += nb) {
#pragma unroll
        for (int i = 0; i < 4; ++i) {
            const int row = task * 16 + w * 4 + i;  // < 32000
            const float4* wr = (const float4*)P.Wout + (size_t)row * (H / 4);
            float a = 0.f;
#pragma unroll
            for (int it = 0; it < 4; ++it) {
                const int idx = it * 64 + lane;
                float4 wv = wr[idx], x = hn4[idx];
                a += wv.x * x.x + wv.y * x.y + wv.z * x.z + wv.w * x.w;
            }
            a = wave_sum(a) + P.bout[row];  // identical on all lanes
            if (lane == 0) P.out[row] = a;
            const float mn = fmaxf(m, a);
            ssum = ssum * expf(m - mn) + expf(a - mn);
            m = mn;
        }
    }
    const int wg = bid * 4 + w;
    if (lane == 0) { P.partm[wg] = m; P.parts[wg] = ssum; }  // idle: -inf/0
}

// P3: global (max, log-sum-exp) over nw wave-partials (redundant per block,
// fixed order => deterministic) + in-place log-softmax.
__device__ void phase3(const Ptrs& P, int nb, int nw, int bid, int t, int lane, int w,
                       float* red) {
    float m = -3.4e38f;
    for (int k = t; k < nw; k += NTHR) m = fmaxf(m, P.partm[k]);
    m = wave_max(m);
    if (lane == 0) red[w] = m;
    __syncthreads();
    const float M = fmaxf(fmaxf(red[0], red[1]), fmaxf(red[2], red[3]));
    float s = 0.f;
    for (int k = t; k < nw; k += NTHR) s += P.parts[k] * expf(P.partm[k] - M);
    s = wave_sum(s);
    __syncthreads();
    if (lane == 0) red[w] = s;
    __syncthreads();
    const float L = logf(red[0] + red[1] + red[2] + red[3]);
    for (int task = bid; task < P3_TASKS; task += nb) {
        const int g = task * NTHR + t;
        P.out[g] -= (M + L);
    }
}

__global__ __launch_bounds__(NTHR, 4) void coop_kernel(Ptrs P, int nb) {
    __shared__ float4 rn[H / 4];
    __shared__ float hnew[H];
    __shared__ float red[4];
    cg::grid_group g = cg::this_grid();
    const int bid = blockIdx.x, t = threadIdx.x, lane = t & 63, w = t >> 6;
    phase0(P, nb, bid, t, lane, w);
    g.sync();
    phase1(P, nb, bid, t, lane, w, rn);
    g.sync();
    phase2(P, nb, bid, t, lane, w, hnew);
    g.sync();
    phase3(P, nb, nb * 4, bid, t, lane, w, red);
}

__global__ __launch_bounds__(NTHR, 4) void phase_kernel(Ptrs P, int nb, int nw, int phase) {
    __shared__ float4 rn[H / 4];
    __shared__ float hnew[H];
    __shared__ float red[4];
    const int bid = blockIdx.x, t = threadIdx.x, lane = t & 63, w = t >> 6;
    if (phase == 0) phase0(P, nb, bid, t, lane, w);
    else if (phase == 1) phase1(P, nb, bid, t, lane, w, rn);
    else if (phase == 2) phase2(P, nb, bid, t, lane, w, hnew);
    else phase3(P, nb, nw, bid, t, lane, w, red);
}

extern "C" void kernel_launch(void* const* d_in, const int* in_sizes, int n_in,
                              void* d_out, int out_size, void* d_ws, size_t ws_size,
                              hipStream_t stream) {
    Ptrs P;
    P.word = (const int*)d_in[0];
    P.hin  = (const float*)d_in[1];
    P.enc  = (const float*)d_in[2];
    P.emb  = (const float*)d_in[3];
    // d_in[4] attn_W, d_in[5] attn_b: dead (softmax over size-1 axis)
    P.Wih  = (const float*)d_in[6];
    P.Whh  = (const float*)d_in[7];
    P.bih  = (const float*)d_in[8];
    P.bhh  = (const float*)d_in[9];
    P.Wout = (const float*)d_in[10];
    P.bout = (const float*)d_in[11];
    P.out  = (float*)d_out;
    float* ws = (float*)d_ws;
    P.part  = ws;                       // [32*1024]
    P.gi    = P.part + CS_TASKS * H;    // [3072]
    P.gh    = P.gi + 3 * H;             // [3072]
    P.partm = P.gh + 3 * H;             // [MAXW]
    P.parts = P.partm + MAXW;           // [MAXW]

    // Host-side device queries: no stream ops, graph-capture safe.
    int dev = 0;
    (void)hipGetDevice(&dev);
    int coop = 0;
    (void)hipDeviceGetAttribute(&coop, hipDeviceAttributeCooperativeLaunch, dev);
    int ncu = 0;
    (void)hipDeviceGetAttribute(&ncu, hipDeviceAttributeMultiprocessorCount, dev);
    int maxblk = 0;
    if (hipOccupancyMaxActiveBlocksPerMultiprocessor(&maxblk, coop_kernel, NTHR, 0)
        != hipSuccess)
        maxblk = 0;

    bool done = false;
    if (coop && ncu > 0 && maxblk > 0) {
        int nb = ncu * maxblk;
        if (nb > MAXNB) nb = MAXNB;
        void* args[] = {(void*)&P, (void*)&nb};
        done = hipLaunchCooperativeKernel((void*)coop_kernel, dim3(nb), dim3(NTHR),
                                          args, 0, stream) == hipSuccess;
    }
    if (!done) {
        const int nw = P2_TASKS * 4;  // waves writing partials in phase 2
        phase_kernel<<<P0_TASKS, NTHR, 0, stream>>>(P, P0_TASKS, nw, 0);
        phase_kernel<<<MV_TASKS, NTHR, 0, stream>>>(P, MV_TASKS, nw, 1);
        phase_kernel<<<P2_TASKS, NTHR, 0, stream>>>(P, P2_TASKS, nw, 2);
        phase_kernel<<<P3_TASKS, NTHR, 0, stream>>>(P, P3_TASKS, nw, 3);
    }
}